// Round 1
// baseline (284.535 us; speedup 1.0000x reference)
//
#include <hip/hip_runtime.h>
#include <hip/hip_bf16.h>

typedef __bf16 bf16;
typedef __bf16 bf16x8 __attribute__((ext_vector_type(8)));
typedef __bf16 bf16x4 __attribute__((ext_vector_type(4)));
typedef float f32x4 __attribute__((ext_vector_type(4)));
typedef unsigned short ushort4v __attribute__((ext_vector_type(4)));

#define HID 1024
#define SEQL 2048
#define NB 4

// ---------------- cast fp32 -> bf16, vectorized ----------------
__global__ __launch_bounds__(256) void cast_f32_to_bf16(const float* __restrict__ in,
                                                        bf16* __restrict__ out, int n4) {
  int i = blockIdx.x * 256 + threadIdx.x;
  if (i < n4) {
    float4 v = reinterpret_cast<const float4*>(in)[i];
    bf16x4 o = { (bf16)v.x, (bf16)v.y, (bf16)v.z, (bf16)v.w };
    reinterpret_cast<bf16x4*>(out)[i] = o;
  }
}

// ---------------- NT GEMM: C[M,N] = A[M,K] * B[N,K]^T (+bias) * scale ----------------
// m97 structure: 128x128 tile, BK=32, 256 threads (4 waves, 2x2), global_load_lds w16.
template <typename OutT, bool BIAS, bool CSKIP, bool KLIM>
__global__ __launch_bounds__(256)
void gemm_nt(const bf16* __restrict__ A, const bf16* __restrict__ B,
             const float* __restrict__ bias, OutT* __restrict__ C,
             int K, int N, long sA, long sB, long sC, float scale) {
  const int bj = blockIdx.x, bi = blockIdx.y, bz = blockIdx.z;
  if (CSKIP && bj > bi) return;  // fully-masked upper-triangle tile: never read downstream
  A += (long)bz * sA + (long)bi * 128 * K;
  B += (long)bz * sB + (long)bj * 128 * K;
  C += (long)bz * sC;
  const int Kend = KLIM ? ((bi + 1) * 128) : K;  // causal K-limit (attn rows j>i are 0)

  __shared__ bf16 As[128 * 32];
  __shared__ bf16 Bs[128 * 32];

  const int t = threadIdx.x;
  const int lane = t & 63;
  const int wid = t >> 6;
  const int wr = (wid >> 1) * 64;   // wave row offset in tile
  const int wc = (wid & 1) * 64;    // wave col offset in tile
  const int frow = lane & 15;       // fragment row within 16x16
  const int fkb = (lane >> 4) * 8;  // fragment k offset (8 contiguous bf16)

  // staging: thread t loads 16B; issue0 rows 0..63, issue1 rows 64..127
  const int r0 = t >> 2;
  const int c0 = (t & 3) * 8;

  f32x4 acc[4][4] = {};

  for (int k0 = 0; k0 < Kend; k0 += 32) {
    const bf16* ga0 = A + (long)r0 * K + k0 + c0;
    const bf16* ga1 = A + (long)(r0 + 64) * K + k0 + c0;
    const bf16* gb0 = B + (long)r0 * K + k0 + c0;
    const bf16* gb1 = B + (long)(r0 + 64) * K + k0 + c0;
    __builtin_amdgcn_global_load_lds((const __attribute__((address_space(1))) void*)ga0,
                                     (__attribute__((address_space(3))) void*)(As + t * 8), 16, 0, 0);
    __builtin_amdgcn_global_load_lds((const __attribute__((address_space(1))) void*)ga1,
                                     (__attribute__((address_space(3))) void*)(As + 2048 + t * 8), 16, 0, 0);
    __builtin_amdgcn_global_load_lds((const __attribute__((address_space(1))) void*)gb0,
                                     (__attribute__((address_space(3))) void*)(Bs + t * 8), 16, 0, 0);
    __builtin_amdgcn_global_load_lds((const __attribute__((address_space(1))) void*)gb1,
                                     (__attribute__((address_space(3))) void*)(Bs + 2048 + t * 8), 16, 0, 0);
    __syncthreads();

    bf16x8 af[4], bfr[4];
#pragma unroll
    for (int m = 0; m < 4; ++m)
      af[m] = *reinterpret_cast<const bf16x8*>(&As[(wr + m * 16 + frow) * 32 + fkb]);
#pragma unroll
    for (int n = 0; n < 4; ++n)
      bfr[n] = *reinterpret_cast<const bf16x8*>(&Bs[(wc + n * 16 + frow) * 32 + fkb]);
#pragma unroll
    for (int m = 0; m < 4; ++m)
#pragma unroll
      for (int n = 0; n < 4; ++n)
        acc[m][n] = __builtin_amdgcn_mfma_f32_16x16x32_bf16(af[m], bfr[n], acc[m][n], 0, 0, 0);
    __syncthreads();
  }

  // epilogue: C/D layout col=lane&15, row=(lane>>4)*4+r  (guide-verified m89/m91)
  const int crow = (lane >> 4) * 4;
  const int ccol = lane & 15;
  const int rowg0 = bi * 128 + wr;
  const int colg0 = bj * 128 + wc;
#pragma unroll
  for (int m = 0; m < 4; ++m) {
#pragma unroll
    for (int n = 0; n < 4; ++n) {
      const int col = colg0 + n * 16 + ccol;
      const float bv = BIAS ? bias[col] : 0.0f;
#pragma unroll
      for (int r = 0; r < 4; ++r) {
        const int row = rowg0 + m * 16 + crow + r;
        float v = (acc[m][n][r] + bv) * scale;
        C[(long)row * N + col] = (OutT)v;
      }
    }
  }
}

// ---------------- causal softmax: fp32 scores row -> bf16 probs (zeros above diag) ----------------
__global__ __launch_bounds__(256) void softmax_causal(const float* __restrict__ S,
                                                      bf16* __restrict__ P) {
  const int lane = threadIdx.x & 63;
  const int wid = threadIdx.x >> 6;
  const long row = (long)blockIdx.x * 4 + wid;  // 0 .. NB*SEQL-1
  const int i = (int)(row & (SEQL - 1));
  const float* src = S + row * SEQL;
  bf16* dst = P + row * SEQL;
  const float NEG = -__builtin_inff();

  float4 v[8];
  float m = NEG;
#pragma unroll
  for (int c = 0; c < 8; ++c) {
    const int j0 = c * 256 + lane * 4;
    if (j0 <= i) {
      float4 x = *reinterpret_cast<const float4*>(src + j0);
      v[c].x = x.x;
      v[c].y = (j0 + 1 <= i) ? x.y : NEG;
      v[c].z = (j0 + 2 <= i) ? x.z : NEG;
      v[c].w = (j0 + 3 <= i) ? x.w : NEG;
    } else {
      v[c] = make_float4(NEG, NEG, NEG, NEG);
    }
    m = fmaxf(m, fmaxf(fmaxf(v[c].x, v[c].y), fmaxf(v[c].z, v[c].w)));
  }
#pragma unroll
  for (int off = 32; off > 0; off >>= 1) m = fmaxf(m, __shfl_xor(m, off));

  float s = 0.f;
#pragma unroll
  for (int c = 0; c < 8; ++c) {
    v[c].x = __expf(v[c].x - m);
    v[c].y = __expf(v[c].y - m);
    v[c].z = __expf(v[c].z - m);
    v[c].w = __expf(v[c].w - m);
    s += v[c].x + v[c].y + v[c].z + v[c].w;
  }
#pragma unroll
  for (int off = 32; off > 0; off >>= 1) s += __shfl_xor(s, off);
  const float inv = 1.f / s;

#pragma unroll
  for (int c = 0; c < 8; ++c) {
    const int j0 = c * 256 + lane * 4;
    bf16x4 o = { (bf16)(v[c].x * inv), (bf16)(v[c].y * inv),
                 (bf16)(v[c].z * inv), (bf16)(v[c].w * inv) };
    *reinterpret_cast<bf16x4*>(dst + j0) = o;
  }
}

// ---------------- bf16 64x64 tiled transpose: V[b][s][h] -> VT[b][h][s] ----------------
__global__ __launch_bounds__(256) void transpose64(const bf16* __restrict__ V,
                                                   bf16* __restrict__ VT) {
  __shared__ bf16 tile[64][72];
  const int b = blockIdx.z;
  const int s0 = blockIdx.x * 64;
  const int h0 = blockIdx.y * 64;
  const int t = threadIdx.x;
  const int r = t >> 4;
  const int c = (t & 15) * 4;
  const bf16* src = V + ((long)b * SEQL + s0) * HID + h0;
#pragma unroll
  for (int rr = 0; rr < 4; ++rr) {
    const int row = r + rr * 16;
    *reinterpret_cast<ushort4v*>(&tile[row][c]) =
        *reinterpret_cast<const ushort4v*>(src + (long)row * HID + c);
  }
  __syncthreads();
  bf16* dst = VT + ((long)b * HID + h0) * SEQL + s0;
#pragma unroll
  for (int rr = 0; rr < 4; ++rr) {
    const int hr = r + rr * 16;
    bf16x4 o = { tile[c + 0][hr], tile[c + 1][hr], tile[c + 2][hr], tile[c + 3][hr] };
    *reinterpret_cast<bf16x4*>(dst + (long)hr * SEQL + c) = o;
  }
}

extern "C" void kernel_launch(void* const* d_in, const int* in_sizes, int n_in,
                              void* d_out, int out_size, void* d_ws, size_t ws_size,
                              hipStream_t stream) {
  const float* x  = (const float*)d_in[0];
  const float* Wq = (const float*)d_in[1];
  const float* bq = (const float*)d_in[2];
  const float* Wk = (const float*)d_in[3];
  const float* bk = (const float*)d_in[4];
  const float* Wv = (const float*)d_in[5];
  const float* bv = (const float*)d_in[6];
  const float* Wo = (const float*)d_in[7];
  const float* bo = (const float*)d_in[8];
  float* out = (float*)d_out;

  // workspace layout (136 MiB) with lifetime-safe aliasing:
  //  [0        , 33.55MB) AT  (attn bf16)   -- aliases XB[0,16.78) + Q[16.78,33.55)
  //  [33.55MB  , 50.33MB) Kb  (k bf16)      -- aliases CTX (written after K dead)
  //  [50.33MB  , 67.11MB) VT
  //  [67.11MB  , 75.50MB) WQB WKB WVB WOB
  //  [75.50MB  ,142.61MB) SC  (scores f32)  -- V aliases SC tail (V dead before SC written)
  char* ws = (char*)d_ws;
  bf16*  AT  = (bf16*)(ws);
  bf16*  XB  = (bf16*)(ws);
  bf16*  Q   = (bf16*)(ws + 16777216L);
  bf16*  Kb  = (bf16*)(ws + 33554432L);
  bf16*  CTX = (bf16*)(ws + 33554432L);
  bf16*  VT  = (bf16*)(ws + 50331648L);
  bf16*  WQB = (bf16*)(ws + 67108864L);
  bf16*  WKB = (bf16*)(ws + 69206016L);
  bf16*  WVB = (bf16*)(ws + 71303168L);
  bf16*  WOB = (bf16*)(ws + 73400320L);
  float* SC  = (float*)(ws + 75497472L);
  bf16*  V   = (bf16*)(ws + 75497472L + 50331648L);

  const long MS = (long)NB * SEQL;  // 8192 rows

  // 1) casts
  cast_f32_to_bf16<<<(int)(MS * HID / 4 / 256), 256, 0, stream>>>(x, XB, (int)(MS * HID / 4));
  cast_f32_to_bf16<<<1024, 256, 0, stream>>>(Wq, WQB, HID * HID / 4);
  cast_f32_to_bf16<<<1024, 256, 0, stream>>>(Wk, WKB, HID * HID / 4);
  cast_f32_to_bf16<<<1024, 256, 0, stream>>>(Wv, WVB, HID * HID / 4);
  cast_f32_to_bf16<<<1024, 256, 0, stream>>>(Wo, WOB, HID * HID / 4);

  // 2) projections (q gets 1/sqrt(H) folded in, after bias)
  dim3 gP(HID / 128, MS / 128, 1);
  gemm_nt<bf16, true, false, false><<<gP, 256, 0, stream>>>(XB, WQB, bq, Q, HID, HID, 0, 0, 0, 1.0f / 32.0f);
  gemm_nt<bf16, true, false, false><<<gP, 256, 0, stream>>>(XB, WKB, bk, Kb, HID, HID, 0, 0, 0, 1.0f);
  gemm_nt<bf16, true, false, false><<<gP, 256, 0, stream>>>(XB, WVB, bv, V, HID, HID, 0, 0, 0, 1.0f);

  // 3) v -> vT (per batch), so PV is NT-form
  transpose64<<<dim3(SEQL / 64, HID / 64, NB), 256, 0, stream>>>(V, VT);

  // 4) scores = q . k^T  (q pre-scaled), fp32, skip upper-triangle tiles
  dim3 gS(SEQL / 128, SEQL / 128, NB);
  gemm_nt<float, false, true, false><<<gS, 256, 0, stream>>>(
      Q, Kb, nullptr, SC, HID, SEQL, (long)SEQL * HID, (long)SEQL * HID, (long)SEQL * SEQL, 1.0f);

  // 5) causal softmax -> bf16 probs (zeros above diagonal)
  softmax_causal<<<(int)(MS / 4), 256, 0, stream>>>(SC, AT);

  // 6) ctx = attn @ v   (causal K-limit per row-tile)
  dim3 gV(HID / 128, SEQL / 128, NB);
  gemm_nt<bf16, false, false, true><<<gV, 256, 0, stream>>>(
      AT, VT, nullptr, CTX, SEQL, HID, (long)SEQL * SEQL, (long)SEQL * HID, (long)SEQL * HID, 1.0f);

  // 7) out = ctx @ Wo^T + bo  (fp32 -> d_out)
  gemm_nt<float, true, false, false><<<gP, 256, 0, stream>>>(CTX, WOB, bo, out, HID, HID, 0, 0, 0, 1.0f);
}

// Round 2
// 257.551 us; speedup vs baseline: 1.1048x; 1.1048x over previous
//
#include <hip/hip_runtime.h>
#include <hip/hip_bf16.h>

typedef __bf16 bf16;
typedef __bf16 bf16x8 __attribute__((ext_vector_type(8)));
typedef __bf16 bf16x4 __attribute__((ext_vector_type(4)));
typedef float f32x4 __attribute__((ext_vector_type(4)));
typedef unsigned short ushort4v __attribute__((ext_vector_type(4)));

#define HID 1024
#define SEQL 2048
#define NB 4

// ---------------- cast fp32 -> bf16, vectorized ----------------
__global__ __launch_bounds__(256) void cast_f32_to_bf16(const float* __restrict__ in,
                                                        bf16* __restrict__ out, int n4) {
  int i = blockIdx.x * 256 + threadIdx.x;
  if (i < n4) {
    float4 v = reinterpret_cast<const float4*>(in)[i];
    bf16x4 o = { (bf16)v.x, (bf16)v.y, (bf16)v.z, (bf16)v.w };
    reinterpret_cast<bf16x4*>(out)[i] = o;
  }
}

// ---------------- concat q/k/v biases into one fp32 vector [3072] ----------------
__global__ __launch_bounds__(256) void concat_bias(const float* __restrict__ bq,
                                                   const float* __restrict__ bk,
                                                   const float* __restrict__ bv,
                                                   float* __restrict__ o) {
  int i = blockIdx.x * 256 + threadIdx.x;  // 12 blocks * 256 = 3072
  o[i] = (i < HID) ? bq[i] : (i < 2 * HID ? bk[i - HID] : bv[i - 2 * HID]);
}

// ---------------- NT GEMM: C[M,N] = A[M,K] * B[N,K]^T (+bias) * scale ----------------
// 128x128 tile, BK=32, 4 waves, global_load_lds w16, 2-phase double-buffered pipeline
// (T3 minimum recipe: STAGE next-tile before compute, one barrier per K-step).
template <typename OutT, bool BIAS, bool CSKIP, bool KLIM, bool PACKED, bool QKVSC>
__global__ __launch_bounds__(256)
void gemm_nt(const bf16* __restrict__ A, const bf16* __restrict__ B,
             const float* __restrict__ bias, OutT* __restrict__ C,
             int K, int lda, int ldb, int N, long sA, long sB, long sC, float scale) {
  const int bj = blockIdx.x, bi = blockIdx.y, bz = blockIdx.z;
  if (CSKIP && bj > bi) return;  // fully-masked upper-triangle tile: never read downstream
  A += (long)bz * sA + (long)bi * 128 * lda;
  B += (long)bz * sB + (long)bj * 128 * ldb;
  const int Kend = KLIM ? ((bi + 1) * 128) : K;  // causal K-limit

  __shared__ bf16 As[2][128 * 32];
  __shared__ bf16 Bs[2][128 * 32];

  const int t = threadIdx.x;
  const int lane = t & 63;
  const int wid = t >> 6;
  const int wr = (wid >> 1) * 64;   // wave row offset in tile
  const int wc = (wid & 1) * 64;    // wave col offset in tile
  const int frow = lane & 15;       // fragment row within 16x16
  const int fkb = (lane >> 4) * 8;  // fragment k offset
  const int r0 = t >> 2;            // staging row
  const int c0 = (t & 3) * 8;       // staging col (bf16)

  const long a0off = (long)r0 * lda + c0;
  const long a1off = (long)(r0 + 64) * lda + c0;
  const long b0off = (long)r0 * ldb + c0;
  const long b1off = (long)(r0 + 64) * ldb + c0;

  f32x4 acc[4][4] = {};

#define STAGE(bufi, kk)                                                                             \
  {                                                                                                 \
    __builtin_amdgcn_global_load_lds(                                                               \
        (const __attribute__((address_space(1))) void*)(A + a0off + (kk)),                          \
        (__attribute__((address_space(3))) void*)(&As[bufi][t * 8]), 16, 0, 0);                     \
    __builtin_amdgcn_global_load_lds(                                                               \
        (const __attribute__((address_space(1))) void*)(A + a1off + (kk)),                          \
        (__attribute__((address_space(3))) void*)(&As[bufi][2048 + t * 8]), 16, 0, 0);              \
    __builtin_amdgcn_global_load_lds(                                                               \
        (const __attribute__((address_space(1))) void*)(B + b0off + (kk)),                          \
        (__attribute__((address_space(3))) void*)(&Bs[bufi][t * 8]), 16, 0, 0);                     \
    __builtin_amdgcn_global_load_lds(                                                               \
        (const __attribute__((address_space(1))) void*)(B + b1off + (kk)),                          \
        (__attribute__((address_space(3))) void*)(&Bs[bufi][2048 + t * 8]), 16, 0, 0);              \
  }

#define COMPUTE(bufi)                                                                               \
  {                                                                                                 \
    bf16x8 af[4], bfr[4];                                                                           \
    _Pragma("unroll") for (int m = 0; m < 4; ++m)                                                   \
        af[m] = *reinterpret_cast<const bf16x8*>(&As[bufi][(wr + m * 16 + frow) * 32 + fkb]);       \
    _Pragma("unroll") for (int n = 0; n < 4; ++n)                                                   \
        bfr[n] = *reinterpret_cast<const bf16x8*>(&Bs[bufi][(wc + n * 16 + frow) * 32 + fkb]);      \
    _Pragma("unroll") for (int m = 0; m < 4; ++m)                                                   \
      _Pragma("unroll") for (int n = 0; n < 4; ++n)                                                 \
          acc[m][n] = __builtin_amdgcn_mfma_f32_16x16x32_bf16(af[m], bfr[n], acc[m][n], 0, 0, 0);   \
  }

  STAGE(0, 0);
  __syncthreads();  // compiler-emitted vmcnt(0) drain makes buf0 visible
  int cur = 0;
  const int nk = Kend >> 5;
  for (int it = 0; it < nk - 1; ++it) {
    STAGE(cur ^ 1, (it + 1) * 32);  // prefetch next tile; flies under compute
    COMPUTE(cur);
    __syncthreads();                // single barrier per K-step (drains vm+lgkm)
    cur ^= 1;
  }
  COMPUTE(cur);
#undef STAGE
#undef COMPUTE

  // epilogue: C/D layout col=lane&15, row=(lane>>4)*4+r
  const int crow = (lane >> 4) * 4;
  const int ccol = lane & 15;
  OutT* Cp = PACKED
                 ? C + ((long)(bz * 136 + (bi * (bi + 1)) / 2 + bj)) * (128 * 128)
                 : C + (long)bz * sC;
#pragma unroll
  for (int m = 0; m < 4; ++m) {
#pragma unroll
    for (int n = 0; n < 4; ++n) {
      const int coll = wc + n * 16 + ccol;
      const int colg = bj * 128 + coll;
      const float bv = BIAS ? bias[colg] : 0.0f;
      const float sc = QKVSC ? (colg < HID ? 0.03125f : 1.0f) : scale;
#pragma unroll
      for (int r = 0; r < 4; ++r) {
        const int rowl = wr + m * 16 + crow + r;
        const float v = (acc[m][n][r] + bv) * sc;
        if (PACKED)
          Cp[(long)rowl * 128 + coll] = (OutT)v;
        else
          Cp[(long)(bi * 128 + rowl) * N + colg] = (OutT)v;
      }
    }
  }
}

// ---------------- causal softmax: packed-triangular fp32 scores -> bf16 probs ----------------
__global__ __launch_bounds__(256) void softmax_causal(const float* __restrict__ SC,
                                                      bf16* __restrict__ P) {
  const int lane = threadIdx.x & 63;
  const int wid = threadIdx.x >> 6;
  const long row = (long)blockIdx.x * 4 + wid;  // 0 .. NB*SEQL-1
  const int b = (int)(row >> 11);
  const int i = (int)(row & (SEQL - 1));
  const int bi = i >> 7;
  const long triBase = (long)(b * 136 + (bi * (bi + 1)) / 2) * 16384 + (long)(i & 127) * 128;
  bf16* dst = P + row * SEQL;
  const float NEG = -__builtin_inff();
  const int kend = i | 127;  // last col of diagonal tile

  float4 v[8];
  float m = NEG;
#pragma unroll
  for (int c = 0; c < 8; ++c) {
    const int j0 = c * 256 + lane * 4;
    if (j0 <= i) {
      const int bj = j0 >> 7;
      float4 x = *reinterpret_cast<const float4*>(SC + triBase + (long)bj * 16384 + (j0 & 127));
      v[c].x = x.x;
      v[c].y = (j0 + 1 <= i) ? x.y : NEG;
      v[c].z = (j0 + 2 <= i) ? x.z : NEG;
      v[c].w = (j0 + 3 <= i) ? x.w : NEG;
    } else {
      v[c] = make_float4(NEG, NEG, NEG, NEG);
    }
    m = fmaxf(m, fmaxf(fmaxf(v[c].x, v[c].y), fmaxf(v[c].z, v[c].w)));
  }
#pragma unroll
  for (int off = 32; off > 0; off >>= 1) m = fmaxf(m, __shfl_xor(m, off));

  float s = 0.f;
#pragma unroll
  for (int c = 0; c < 8; ++c) {
    v[c].x = __expf(v[c].x - m);
    v[c].y = __expf(v[c].y - m);
    v[c].z = __expf(v[c].z - m);
    v[c].w = __expf(v[c].w - m);
    s += v[c].x + v[c].y + v[c].z + v[c].w;
  }
#pragma unroll
  for (int off = 32; off > 0; off >>= 1) s += __shfl_xor(s, off);
  const float inv = 1.f / s;

#pragma unroll
  for (int c = 0; c < 8; ++c) {
    const int j0 = c * 256 + lane * 4;
    if (j0 <= kend) {  // PV never reads beyond the diagonal tile (KLIM)
      bf16x4 o = { (bf16)(v[c].x * inv), (bf16)(v[c].y * inv),
                   (bf16)(v[c].z * inv), (bf16)(v[c].w * inv) };
      *reinterpret_cast<bf16x4*>(dst + j0) = o;
    }
  }
}

// ---------------- bf16 64x64 tiled transpose: V[b][s][h] (stride ldv) -> VT[b][h][s] ----------------
__global__ __launch_bounds__(256) void transpose64(const bf16* __restrict__ V,
                                                   bf16* __restrict__ VT, int ldv) {
  __shared__ bf16 tile[64][72];
  const int b = blockIdx.z;
  const int s0 = blockIdx.x * 64;
  const int h0 = blockIdx.y * 64;
  const int t = threadIdx.x;
  const int r = t >> 4;
  const int c = (t & 15) * 4;
  const bf16* src = V + ((long)b * SEQL + s0) * ldv + h0;
#pragma unroll
  for (int rr = 0; rr < 4; ++rr) {
    const int row = r + rr * 16;
    *reinterpret_cast<ushort4v*>(&tile[row][c]) =
        *reinterpret_cast<const ushort4v*>(src + (long)row * ldv + c);
  }
  __syncthreads();
  bf16* dst = VT + ((long)b * HID + h0) * SEQL + s0;
#pragma unroll
  for (int rr = 0; rr < 4; ++rr) {
    const int hr = r + rr * 16;
    bf16x4 o = { tile[c + 0][hr], tile[c + 1][hr], tile[c + 2][hr], tile[c + 3][hr] };
    *reinterpret_cast<bf16x4*>(dst + (long)hr * SEQL + c) = o;
  }
}

extern "C" void kernel_launch(void* const* d_in, const int* in_sizes, int n_in,
                              void* d_out, int out_size, void* d_ws, size_t ws_size,
                              hipStream_t stream) {
  const float* x  = (const float*)d_in[0];
  const float* Wq = (const float*)d_in[1];
  const float* bq = (const float*)d_in[2];
  const float* Wk = (const float*)d_in[3];
  const float* bk = (const float*)d_in[4];
  const float* Wv = (const float*)d_in[5];
  const float* bv = (const float*)d_in[6];
  const float* Wo = (const float*)d_in[7];
  const float* bo = (const float*)d_in[8];
  float* out = (float*)d_out;

  // workspace layout (138.4 MiB peak), lifetime-safe aliasing:
  //  [0      ,33.55M) XB[0,16.78)+WQKVB[16.78,23.07)+bqkv — later AT (all dead after QKV gemm)
  //  [33.55M ,83.89M) QKV bf16 [8192][3072]  — CTX aliases its head during PV (QKV dead)
  //  [83.89M ,100.66M) VT
  //  [100.66M,102.66M) WOB
  //  [102.66M,138.36M) SC packed lower-tri fp32 (4*136 tiles of 128x128)
  char* ws = (char*)d_ws;
  bf16*  XB    = (bf16*)(ws);
  bf16*  WQKVB = (bf16*)(ws + 16777216L);
  float* bqkv  = (float*)(ws + 23068672L);
  bf16*  AT    = (bf16*)(ws);
  bf16*  QKV   = (bf16*)(ws + 33554432L);
  bf16*  CTX   = (bf16*)(ws + 33554432L);
  bf16*  VT    = (bf16*)(ws + 83886080L);
  bf16*  WOB   = (bf16*)(ws + 100663296L);
  float* SCp   = (float*)(ws + 102760448L);

  const long MS = (long)NB * SEQL;  // 8192 rows

  // 1) casts + bias concat
  cast_f32_to_bf16<<<(int)(MS * HID / 4 / 256), 256, 0, stream>>>(x, XB, (int)(MS * HID / 4));
  cast_f32_to_bf16<<<1024, 256, 0, stream>>>(Wq, WQKVB, HID * HID / 4);
  cast_f32_to_bf16<<<1024, 256, 0, stream>>>(Wk, WQKVB + HID * HID, HID * HID / 4);
  cast_f32_to_bf16<<<1024, 256, 0, stream>>>(Wv, WQKVB + 2 * HID * HID, HID * HID / 4);
  cast_f32_to_bf16<<<1024, 256, 0, stream>>>(Wo, WOB, HID * HID / 4);
  concat_bias<<<12, 256, 0, stream>>>(bq, bk, bv, bqkv);

  // 2) fused QKV projection: [8192,1024] x [3072,1024]^T -> [8192,3072]; q-cols scaled 1/32
  gemm_nt<bf16, true, false, false, false, true><<<dim3(24, 64, 1), 256, 0, stream>>>(
      XB, WQKVB, bqkv, QKV, HID, HID, HID, 3 * HID, 0, 0, 0, 1.0f);

  // 3) v -> vT (per batch)
  transpose64<<<dim3(SEQL / 64, HID / 64, NB), 256, 0, stream>>>(QKV + 2 * HID, VT, 3 * HID);

  // 4) scores = q.k^T -> packed lower-tri fp32
  gemm_nt<float, false, true, false, true, false><<<dim3(16, 16, NB), 256, 0, stream>>>(
      QKV, QKV + HID, nullptr, SCp, HID, 3 * HID, 3 * HID, SEQL,
      (long)SEQL * 3 * HID, (long)SEQL * 3 * HID, 0, 1.0f);

  // 5) causal softmax -> bf16 probs (zeros up to diagonal-tile edge)
  softmax_causal<<<(int)(MS / 4), 256, 0, stream>>>(SCp, AT);

  // 6) ctx = attn @ v (causal K-limit per row-tile)
  gemm_nt<bf16, false, false, true, false, false><<<dim3(HID / 128, SEQL / 128, NB), 256, 0, stream>>>(
      AT, VT, nullptr, CTX, SEQL, SEQL, SEQL, HID,
      (long)SEQL * SEQL, (long)HID * SEQL, (long)SEQL * HID, 1.0f);

  // 7) out = ctx @ Wo^T + bo (fp32 -> d_out)
  gemm_nt<float, true, false, false, false, false><<<dim3(HID / 128, MS / 128, 1), 256, 0, stream>>>(
      CTX, WOB, bo, out, HID, HID, HID, HID, 0, 0, 0, 1.0f);
}

// Round 3
// 219.104 us; speedup vs baseline: 1.2986x; 1.1755x over previous
//
#include <hip/hip_runtime.h>
#include <hip/hip_bf16.h>

typedef __bf16 bf16;
typedef __bf16 bf16x8 __attribute__((ext_vector_type(8)));
typedef __bf16 bf16x4 __attribute__((ext_vector_type(4)));
typedef float f32x4 __attribute__((ext_vector_type(4)));
typedef unsigned short ushort4v __attribute__((ext_vector_type(4)));

#define HID 1024
#define SEQL 2048
#define NB 4

// ---------------- cast fp32 -> bf16, vectorized ----------------
__global__ __launch_bounds__(256) void cast_f32_to_bf16(const float* __restrict__ in,
                                                        bf16* __restrict__ out, int n4) {
  int i = blockIdx.x * 256 + threadIdx.x;
  if (i < n4) {
    float4 v = reinterpret_cast<const float4*>(in)[i];
    bf16x4 o = { (bf16)v.x, (bf16)v.y, (bf16)v.z, (bf16)v.w };
    reinterpret_cast<bf16x4*>(out)[i] = o;
  }
}

// ---------------- concat q/k/v biases into one fp32 vector [3072] ----------------
__global__ __launch_bounds__(256) void concat_bias(const float* __restrict__ bq,
                                                   const float* __restrict__ bk,
                                                   const float* __restrict__ bv,
                                                   float* __restrict__ o) {
  int i = blockIdx.x * 256 + threadIdx.x;
  o[i] = (i < HID) ? bq[i] : (i < 2 * HID ? bk[i - HID] : bv[i - 2 * HID]);
}

// ---------------- NT GEMM, phased counted-vmcnt pipeline ----------------
// C[M,N] = A[M,K] * B[N,K]^T (+bias). Tile 256x128, BK=32, 512 thr = 8 waves (4M x 2N),
// per-wave 64x64. 4 round-robin LDS K-tile buffers (96 KB): compute tile t while
// t+1..t+3 fly; steady-state wait = s_waitcnt vmcnt(6). T2 swizzle: LDS slot
// permuted by ((row>>1)&3) via pre-swizzled global source (gload_lds writes linear).
template <typename OutT, bool BIAS, bool CSKIP, bool KLIM, bool PACKED, bool QKVSC>
__global__ __launch_bounds__(512, 2)
void gemm_nt(const bf16* __restrict__ A, const bf16* __restrict__ B,
             const float* __restrict__ bias, OutT* __restrict__ C,
             int K, int lda, int ldb, int N, long sA, long sB, long sC) {
  const int bj = blockIdx.x, bi = blockIdx.y, bz = blockIdx.z;
  if (CSKIP && bj > 2 * bi + 1) return;  // fully-masked causal block
  A += (long)bz * sA + (long)bi * 256 * lda;
  B += (long)bz * sB + (long)bj * 128 * ldb;
  const int Kend = KLIM ? ((bi + 1) * 256) : K;
  const int nt = Kend >> 5;  // >= 8 for all our shapes

  __shared__ bf16 lds[4][12288];  // per buf: A 256x32 (8192) + B 128x32 (4096)

  const int t = threadIdx.x;
  const int lane = t & 63;
  const int wid = t >> 6;
  const int wm = wid >> 1;  // 0..3 (M)
  const int wn = wid & 1;   // 0..1 (N)
  const int frow = lane & 15;
  const int l = lane >> 4;  // k-slot 0..3 (16B units)

  const int sr = t >> 2;                               // staging row 0..127
  const int scol = (((t & 3) ^ ((t >> 3) & 3)) << 3);  // inverse-swizzled src col

  // fragment LDS element offsets (swizzle applied on read)
  int offA[4], offB[4];
#pragma unroll
  for (int m = 0; m < 4; ++m) {
    const int r = wm * 64 + m * 16 + frow;
    offA[m] = r * 32 + ((l ^ ((r >> 1) & 3)) << 3);
  }
#pragma unroll
  for (int n = 0; n < 4; ++n) {
    const int r = wn * 64 + n * 16 + frow;
    offB[n] = 8192 + r * 32 + ((l ^ ((r >> 1) & 3)) << 3);
  }

  f32x4 acc[4][4] = {};

#define STAGE(tile)                                                                      \
  {                                                                                      \
    const int kk = (tile) << 5;                                                          \
    bf16* lb = &lds[(tile) & 3][0];                                                      \
    __builtin_amdgcn_global_load_lds(                                                    \
        (const __attribute__((address_space(1))) void*)(A + (long)sr * lda + kk + scol), \
        (__attribute__((address_space(3))) void*)(lb + t * 8), 16, 0, 0);                \
    __builtin_amdgcn_global_load_lds(                                                    \
        (const __attribute__((address_space(1))) void*)(A + (long)(sr + 128) * lda + kk + scol), \
        (__attribute__((address_space(3))) void*)(lb + 4096 + t * 8), 16, 0, 0);         \
    __builtin_amdgcn_global_load_lds(                                                    \
        (const __attribute__((address_space(1))) void*)(B + (long)sr * ldb + kk + scol), \
        (__attribute__((address_space(3))) void*)(lb + 8192 + t * 8), 16, 0, 0);         \
  }

  STAGE(0); STAGE(1); STAGE(2);  // 9 loads in flight
  asm volatile("s_waitcnt vmcnt(6)" ::: "memory");  // tile 0 landed
  __builtin_amdgcn_s_barrier();
  __builtin_amdgcn_sched_barrier(0);

  for (int tt = 0; tt < nt; ++tt) {
    const bf16* lb = &lds[tt & 3][0];
    bf16x8 af[4], bfr[4];
#pragma unroll
    for (int m = 0; m < 4; ++m) af[m] = *reinterpret_cast<const bf16x8*>(lb + offA[m]);
#pragma unroll
    for (int n = 0; n < 4; ++n) bfr[n] = *reinterpret_cast<const bf16x8*>(lb + offB[n]);
    if (tt + 3 < nt) STAGE(tt + 3);  // writes buf[(tt-1)&3]: all reads of it done pre-barrier
    __builtin_amdgcn_sched_barrier(0);
    __builtin_amdgcn_s_barrier();
    __builtin_amdgcn_s_setprio(1);
#pragma unroll
    for (int m = 0; m < 4; ++m)
#pragma unroll
      for (int n = 0; n < 4; ++n)
        acc[m][n] = __builtin_amdgcn_mfma_f32_16x16x32_bf16(af[m], bfr[n], acc[m][n], 0, 0, 0);
    __builtin_amdgcn_s_setprio(0);
    // drain exactly to "tile tt+1 landed"; counted, never 0 in steady state
    if (tt + 3 < nt)      { asm volatile("s_waitcnt vmcnt(6)" ::: "memory"); }
    else if (tt + 2 < nt) { asm volatile("s_waitcnt vmcnt(3)" ::: "memory"); }
    else if (tt + 1 < nt) { asm volatile("s_waitcnt vmcnt(0)" ::: "memory"); }
    __builtin_amdgcn_s_barrier();
    __builtin_amdgcn_sched_barrier(0);
  }
#undef STAGE

  // epilogue: C/D frag layout col=lane&15, row=(lane>>4)*4+r
  const int crow = (lane >> 4) * 4;
  const int ccol = lane & 15;
#pragma unroll
  for (int m = 0; m < 4; ++m) {
#pragma unroll
    for (int n = 0; n < 4; ++n) {
      const int coll = wn * 64 + n * 16 + ccol;
      const int colg = bj * 128 + coll;
      const float bv = BIAS ? bias[colg] : 0.0f;
      const float sc = QKVSC ? (colg < HID ? 0.03125f : 1.0f) : 1.0f;
      const int rbase = wm * 64 + m * 16 + crow;  // 0..255, frag never crosses 128-edge
      if (PACKED) {
        const int i128 = 2 * bi + (rbase >> 7);
        if (bj <= i128) {
          float* Cp = (float*)C + ((long)(bz * 136 + (i128 * (i128 + 1)) / 2 + bj)) * 16384 +
                      (long)(rbase & 127) * 128 + coll;
#pragma unroll
          for (int rr = 0; rr < 4; ++rr) Cp[rr * 128] = acc[m][n][rr];
        }
      } else {
#pragma unroll
        for (int rr = 0; rr < 4; ++rr) {
          const long row = (long)bi * 256 + rbase + rr;
          C[(long)bz * sC + row * N + colg] = (OutT)((acc[m][n][rr] + bv) * sc);
        }
      }
    }
  }
}

// ---------------- causal softmax: packed-triangular fp32 scores -> bf16 probs ----------------
__global__ __launch_bounds__(256) void softmax_causal(const float* __restrict__ SC,
                                                      bf16* __restrict__ P) {
  const int lane = threadIdx.x & 63;
  const int wid = threadIdx.x >> 6;
  const long row = (long)blockIdx.x * 4 + wid;
  const int b = (int)(row >> 11);
  const int i = (int)(row & (SEQL - 1));
  const int bi = i >> 7;
  const long triBase = (long)(b * 136 + (bi * (bi + 1)) / 2) * 16384 + (long)(i & 127) * 128;
  bf16* dst = P + row * SEQL;
  const float NEG = -__builtin_inff();
  const int kend = i | 255;  // PV reads through the 256-tile edge (KLIM granularity)

  float4 v[8];
  float m = NEG;
#pragma unroll
  for (int c = 0; c < 8; ++c) {
    const int j0 = c * 256 + lane * 4;
    if (j0 <= i) {
      const int bjt = j0 >> 7;
      float4 x = *reinterpret_cast<const float4*>(SC + triBase + (long)bjt * 16384 + (j0 & 127));
      v[c].x = x.x;
      v[c].y = (j0 + 1 <= i) ? x.y : NEG;
      v[c].z = (j0 + 2 <= i) ? x.z : NEG;
      v[c].w = (j0 + 3 <= i) ? x.w : NEG;
    } else {
      v[c] = make_float4(NEG, NEG, NEG, NEG);
    }
    m = fmaxf(m, fmaxf(fmaxf(v[c].x, v[c].y), fmaxf(v[c].z, v[c].w)));
  }
#pragma unroll
  for (int off = 32; off > 0; off >>= 1) m = fmaxf(m, __shfl_xor(m, off));

  float s = 0.f;
#pragma unroll
  for (int c = 0; c < 8; ++c) {
    v[c].x = __expf(v[c].x - m);
    v[c].y = __expf(v[c].y - m);
    v[c].z = __expf(v[c].z - m);
    v[c].w = __expf(v[c].w - m);
    s += v[c].x + v[c].y + v[c].z + v[c].w;
  }
#pragma unroll
  for (int off = 32; off > 0; off >>= 1) s += __shfl_xor(s, off);
  const float inv = 1.f / s;

#pragma unroll
  for (int c = 0; c < 8; ++c) {
    const int j0 = c * 256 + lane * 4;
    if (j0 <= kend) {
      bf16x4 o = { (bf16)(v[c].x * inv), (bf16)(v[c].y * inv),
                   (bf16)(v[c].z * inv), (bf16)(v[c].w * inv) };
      *reinterpret_cast<bf16x4*>(dst + j0) = o;
    }
  }
}

// ---------------- bf16 64x64 tiled transpose: V[b][s][h] (stride ldv) -> VT[b][h][s] ----------------
__global__ __launch_bounds__(256) void transpose64(const bf16* __restrict__ V,
                                                   bf16* __restrict__ VT, int ldv) {
  __shared__ bf16 tile[64][72];
  const int b = blockIdx.z;
  const int s0 = blockIdx.x * 64;
  const int h0 = blockIdx.y * 64;
  const int t = threadIdx.x;
  const int r = t >> 4;
  const int c = (t & 15) * 4;
  const bf16* src = V + ((long)b * SEQL + s0) * ldv + h0;
#pragma unroll
  for (int rr = 0; rr < 4; ++rr) {
    const int row = r + rr * 16;
    *reinterpret_cast<ushort4v*>(&tile[row][c]) =
        *reinterpret_cast<const ushort4v*>(src + (long)row * ldv + c);
  }
  __syncthreads();
  bf16* dst = VT + ((long)b * HID + h0) * SEQL + s0;
#pragma unroll
  for (int rr = 0; rr < 4; ++rr) {
    const int hr = r + rr * 16;
    bf16x4 o = { tile[c + 0][hr], tile[c + 1][hr], tile[c + 2][hr], tile[c + 3][hr] };
    *reinterpret_cast<bf16x4*>(dst + (long)hr * SEQL + c) = o;
  }
}

extern "C" void kernel_launch(void* const* d_in, const int* in_sizes, int n_in,
                              void* d_out, int out_size, void* d_ws, size_t ws_size,
                              hipStream_t stream) {
  const float* x  = (const float*)d_in[0];
  const float* Wq = (const float*)d_in[1];
  const float* bq = (const float*)d_in[2];
  const float* Wk = (const float*)d_in[3];
  const float* bk = (const float*)d_in[4];
  const float* Wv = (const float*)d_in[5];
  const float* bv = (const float*)d_in[6];
  const float* Wo = (const float*)d_in[7];
  const float* bo = (const float*)d_in[8];
  float* out = (float*)d_out;

  // workspace (138.4 MiB peak), lifetime-safe aliasing as R2:
  char* ws = (char*)d_ws;
  bf16*  XB    = (bf16*)(ws);
  bf16*  WQKVB = (bf16*)(ws + 16777216L);
  float* bqkv  = (float*)(ws + 23068672L);
  bf16*  AT    = (bf16*)(ws);
  bf16*  QKV   = (bf16*)(ws + 33554432L);
  bf16*  CTX   = (bf16*)(ws + 33554432L);
  bf16*  VT    = (bf16*)(ws + 83886080L);
  bf16*  WOB   = (bf16*)(ws + 100663296L);
  float* SCp   = (float*)(ws + 102760448L);

  const long MS = (long)NB * SEQL;  // 8192

  cast_f32_to_bf16<<<(int)(MS * HID / 4 / 256), 256, 0, stream>>>(x, XB, (int)(MS * HID / 4));
  cast_f32_to_bf16<<<1024, 256, 0, stream>>>(Wq, WQKVB, HID * HID / 4);
  cast_f32_to_bf16<<<1024, 256, 0, stream>>>(Wk, WQKVB + HID * HID, HID * HID / 4);
  cast_f32_to_bf16<<<1024, 256, 0, stream>>>(Wv, WQKVB + 2 * HID * HID, HID * HID / 4);
  cast_f32_to_bf16<<<1024, 256, 0, stream>>>(Wo, WOB, HID * HID / 4);
  concat_bias<<<12, 256, 0, stream>>>(bq, bk, bv, bqkv);

  // QKV projection: [8192,1024] x [3072,1024]^T; q-cols scaled 1/32
  gemm_nt<bf16, true, false, false, false, true><<<dim3(24, 32, 1), 512, 0, stream>>>(
      XB, WQKVB, bqkv, QKV, HID, HID, HID, 3 * HID, 0, 0, 0);

  transpose64<<<dim3(SEQL / 64, HID / 64, NB), 256, 0, stream>>>(QKV + 2 * HID, VT, 3 * HID);

  // scores = q.k^T -> packed lower-tri fp32 (128-tile granularity)
  gemm_nt<float, false, true, false, true, false><<<dim3(16, 8, NB), 512, 0, stream>>>(
      QKV, QKV + HID, nullptr, SCp, HID, 3 * HID, 3 * HID, SEQL,
      (long)SEQL * 3 * HID, (long)SEQL * 3 * HID, 0);

  softmax_causal<<<(int)(MS / 4), 256, 0, stream>>>(SCp, AT);

  // ctx = attn @ v (causal K-limit, 256-granular)
  gemm_nt<bf16, false, false, true, false, false><<<dim3(8, 8, NB), 512, 0, stream>>>(
      AT, VT, nullptr, CTX, SEQL, SEQL, SEQL, HID,
      (long)SEQL * SEQL, (long)HID * SEQL, (long)SEQL * HID);

  // out = ctx @ Wo^T + bo
  gemm_nt<float, true, false, false, false, false><<<dim3(8, 32, 1), 512, 0, stream>>>(
      CTX, WOB, bo, out, HID, HID, HID, HID, 0, 0, 0);
}

// Round 4
// 201.888 us; speedup vs baseline: 1.4094x; 1.0853x over previous
//
#include <hip/hip_runtime.h>
#include <hip/hip_bf16.h>

typedef __bf16 bf16;
typedef __bf16 bf16x8 __attribute__((ext_vector_type(8)));
typedef __bf16 bf16x4 __attribute__((ext_vector_type(4)));
typedef float f32x4 __attribute__((ext_vector_type(4)));
typedef unsigned short ushort4v __attribute__((ext_vector_type(4)));

#define HID 1024
#define SEQL 2048
#define NB 4

// ---------------- cast fp32 -> bf16, vectorized ----------------
__global__ __launch_bounds__(256) void cast_f32_to_bf16(const float* __restrict__ in,
                                                        bf16* __restrict__ out, int n4) {
  int i = blockIdx.x * 256 + threadIdx.x;
  if (i < n4) {
    float4 v = reinterpret_cast<const float4*>(in)[i];
    bf16x4 o = { (bf16)v.x, (bf16)v.y, (bf16)v.z, (bf16)v.w };
    reinterpret_cast<bf16x4*>(out)[i] = o;
  }
}

// ---------------- concat q/k/v biases into one fp32 vector [3072] ----------------
__global__ __launch_bounds__(256) void concat_bias(const float* __restrict__ bq,
                                                   const float* __restrict__ bk,
                                                   const float* __restrict__ bv,
                                                   float* __restrict__ o) {
  int i = blockIdx.x * 256 + threadIdx.x;
  o[i] = (i < HID) ? bq[i] : (i < 2 * HID ? bk[i - HID] : bv[i - 2 * HID]);
}

// ---------------- NT GEMM, single-barrier counted-vmcnt pipeline ----------------
// C[M,N] = A[M,K] * B[N,K]^T (+bias). Tile 256x128, BK=32, 512 thr = 8 waves (4M x 2N),
// per-wave 64x64. 3 round-robin LDS K-tile buffers (72 KB -> 2 blocks/CU): compute
// tile t while t+1,t+2 fly; steady-state wait = vmcnt(3); ONE barrier per K-step so
// one wave's MFMA cluster overlaps other waves' ds_reads. T2 swizzle via
// pre-swizzled global source (gload_lds writes linear; read applies same XOR).
template <typename OutT, bool BIAS, bool CSKIP, bool KLIM, bool PACKED, bool QKVSC>
__global__ __launch_bounds__(512, 4)
void gemm_nt(const bf16* __restrict__ A, const bf16* __restrict__ B,
             const float* __restrict__ bias, OutT* __restrict__ C,
             int K, int lda, int ldb, int N, long sA, long sB, long sC) {
  const int bj = blockIdx.x, bi = blockIdx.y, bz = blockIdx.z;
  if (CSKIP && bj > 2 * bi + 1) return;  // fully-masked causal block
  A += (long)bz * sA + (long)bi * 256 * lda;
  B += (long)bz * sB + (long)bj * 128 * ldb;
  const int Kend = KLIM ? ((bi + 1) * 256) : K;
  const int nt = Kend >> 5;  // >= 8 for all our shapes

  __shared__ bf16 lds[3][12288];  // per buf: A 256x32 (8192) + B 128x32 (4096)

  const int t = threadIdx.x;
  const int lane = t & 63;
  const int wid = t >> 6;
  const int wm = wid >> 1;  // 0..3 (M)
  const int wn = wid & 1;   // 0..1 (N)
  const int frow = lane & 15;
  const int l = lane >> 4;  // k-slot 0..3 (16B units)

  const int sr = t >> 2;                               // staging row 0..127
  const int scol = (((t & 3) ^ ((t >> 3) & 3)) << 3);  // inverse-swizzled src col

  // fragment LDS element offsets (swizzle applied on read)
  int offA[4], offB[4];
#pragma unroll
  for (int m = 0; m < 4; ++m) {
    const int r = wm * 64 + m * 16 + frow;
    offA[m] = r * 32 + ((l ^ ((r >> 1) & 3)) << 3);
  }
#pragma unroll
  for (int n = 0; n < 4; ++n) {
    const int r = wn * 64 + n * 16 + frow;
    offB[n] = 8192 + r * 32 + ((l ^ ((r >> 1) & 3)) << 3);
  }

  f32x4 acc[4][4] = {};

#define STAGE(bufi, tile)                                                                \
  {                                                                                      \
    const int kk = (tile) << 5;                                                          \
    bf16* lb = &lds[bufi][0];                                                            \
    __builtin_amdgcn_global_load_lds(                                                    \
        (const __attribute__((address_space(1))) void*)(A + (long)sr * lda + kk + scol), \
        (__attribute__((address_space(3))) void*)(lb + t * 8), 16, 0, 0);                \
    __builtin_amdgcn_global_load_lds(                                                    \
        (const __attribute__((address_space(1))) void*)(A + (long)(sr + 128) * lda + kk + scol), \
        (__attribute__((address_space(3))) void*)(lb + 4096 + t * 8), 16, 0, 0);         \
    __builtin_amdgcn_global_load_lds(                                                    \
        (const __attribute__((address_space(1))) void*)(B + (long)sr * ldb + kk + scol), \
        (__attribute__((address_space(3))) void*)(lb + 8192 + t * 8), 16, 0, 0);         \
  }

  STAGE(0, 0);
  STAGE(1, 1);                                      // 6 loads in flight
  asm volatile("s_waitcnt vmcnt(3)" ::: "memory");  // tile 0 landed
  __builtin_amdgcn_s_barrier();
  __builtin_amdgcn_sched_barrier(0);

  int rb = 0;  // buffer holding tile tt
  for (int tt = 0; tt < nt; ++tt) {
    const bf16* lb = &lds[rb][0];
    bf16x8 af[4], bfr[4];
#pragma unroll
    for (int m = 0; m < 4; ++m) af[m] = *reinterpret_cast<const bf16x8*>(lb + offA[m]);
#pragma unroll
    for (int n = 0; n < 4; ++n) bfr[n] = *reinterpret_cast<const bf16x8*>(lb + offB[n]);
    int sb = rb + 2; if (sb >= 3) sb -= 3;
    if (tt + 2 < nt) STAGE(sb, tt + 2);  // writes buf[(tt-1)%3]: all reads of it done pre-barrier
    __builtin_amdgcn_s_setprio(1);
#pragma unroll
    for (int m = 0; m < 4; ++m)
#pragma unroll
      for (int n = 0; n < 4; ++n)
        acc[m][n] = __builtin_amdgcn_mfma_f32_16x16x32_bf16(af[m], bfr[n], acc[m][n], 0, 0, 0);
    __builtin_amdgcn_s_setprio(0);
    __builtin_amdgcn_sched_barrier(0);
    // drain exactly to "tile tt+1 landed"; counted, never 0 in steady state
    if (tt + 2 < nt)      { asm volatile("s_waitcnt vmcnt(3)" ::: "memory"); }
    else if (tt + 1 < nt) { asm volatile("s_waitcnt vmcnt(0)" ::: "memory"); }
    if (tt + 1 < nt) {
      __builtin_amdgcn_s_barrier();
      __builtin_amdgcn_sched_barrier(0);
    }
    rb = (rb + 1 == 3) ? 0 : rb + 1;
  }
#undef STAGE

  // epilogue: C/D frag layout col=lane&15, row=(lane>>4)*4+r
  const int crow = (lane >> 4) * 4;
  const int ccol = lane & 15;
#pragma unroll
  for (int m = 0; m < 4; ++m) {
#pragma unroll
    for (int n = 0; n < 4; ++n) {
      const int coll = wn * 64 + n * 16 + ccol;
      const int colg = bj * 128 + coll;
      const float bv = BIAS ? bias[colg] : 0.0f;
      const float sc = QKVSC ? (colg < HID ? 0.03125f : 1.0f) : 1.0f;
      const int rbase = wm * 64 + m * 16 + crow;  // 0..255, frag never crosses 128-edge
      if (PACKED) {
        const int i128 = 2 * bi + (rbase >> 7);
        if (bj <= i128) {
          float* Cp = (float*)C + ((long)(bz * 136 + (i128 * (i128 + 1)) / 2 + bj)) * 16384 +
                      (long)(rbase & 127) * 128 + coll;
#pragma unroll
          for (int rr = 0; rr < 4; ++rr) Cp[rr * 128] = acc[m][n][rr];
        }
      } else {
#pragma unroll
        for (int rr = 0; rr < 4; ++rr) {
          const long row = (long)bi * 256 + rbase + rr;
          C[(long)bz * sC + row * N + colg] = (OutT)((acc[m][n][rr] + bv) * sc);
        }
      }
    }
  }
}

// ---------------- causal softmax: packed-triangular fp32 scores -> bf16 probs ----------------
__global__ __launch_bounds__(256) void softmax_causal(const float* __restrict__ SC,
                                                      bf16* __restrict__ P) {
  const int lane = threadIdx.x & 63;
  const int wid = threadIdx.x >> 6;
  const long row = (long)blockIdx.x * 4 + wid;
  const int b = (int)(row >> 11);
  const int i = (int)(row & (SEQL - 1));
  const int bi = i >> 7;
  const long triBase = (long)(b * 136 + (bi * (bi + 1)) / 2) * 16384 + (long)(i & 127) * 128;
  bf16* dst = P + row * SEQL;
  const float NEG = -__builtin_inff();
  const int kend = i | 255;  // PV reads through the 256-tile edge (KLIM granularity)

  float4 v[8];
  float m = NEG;
#pragma unroll
  for (int c = 0; c < 8; ++c) {
    const int j0 = c * 256 + lane * 4;
    if (j0 <= i) {
      const int bjt = j0 >> 7;
      float4 x = *reinterpret_cast<const float4*>(SC + triBase + (long)bjt * 16384 + (j0 & 127));
      v[c].x = x.x;
      v[c].y = (j0 + 1 <= i) ? x.y : NEG;
      v[c].z = (j0 + 2 <= i) ? x.z : NEG;
      v[c].w = (j0 + 3 <= i) ? x.w : NEG;
    } else {
      v[c] = make_float4(NEG, NEG, NEG, NEG);
    }
    m = fmaxf(m, fmaxf(fmaxf(v[c].x, v[c].y), fmaxf(v[c].z, v[c].w)));
  }
#pragma unroll
  for (int off = 32; off > 0; off >>= 1) m = fmaxf(m, __shfl_xor(m, off));

  float s = 0.f;
#pragma unroll
  for (int c = 0; c < 8; ++c) {
    v[c].x = __expf(v[c].x - m);
    v[c].y = __expf(v[c].y - m);
    v[c].z = __expf(v[c].z - m);
    v[c].w = __expf(v[c].w - m);
    s += v[c].x + v[c].y + v[c].z + v[c].w;
  }
#pragma unroll
  for (int off = 32; off > 0; off >>= 1) s += __shfl_xor(s, off);
  const float inv = 1.f / s;

#pragma unroll
  for (int c = 0; c < 8; ++c) {
    const int j0 = c * 256 + lane * 4;
    if (j0 <= kend) {
      bf16x4 o = { (bf16)(v[c].x * inv), (bf16)(v[c].y * inv),
                   (bf16)(v[c].z * inv), (bf16)(v[c].w * inv) };
      *reinterpret_cast<bf16x4*>(dst + j0) = o;
    }
  }
}

// ---------------- bf16 64x64 tiled transpose: V[b][s][h] (stride ldv) -> VT[b][h][s] ----------------
__global__ __launch_bounds__(256) void transpose64(const bf16* __restrict__ V,
                                                   bf16* __restrict__ VT, int ldv) {
  __shared__ bf16 tile[64][72];
  const int b = blockIdx.z;
  const int s0 = blockIdx.x * 64;
  const int h0 = blockIdx.y * 64;
  const int t = threadIdx.x;
  const int r = t >> 4;
  const int c = (t & 15) * 4;
  const bf16* src = V + ((long)b * SEQL + s0) * ldv + h0;
#pragma unroll
  for (int rr = 0; rr < 4; ++rr) {
    const int row = r + rr * 16;
    *reinterpret_cast<ushort4v*>(&tile[row][c]) =
        *reinterpret_cast<const ushort4v*>(src + (long)row * ldv + c);
  }
  __syncthreads();
  bf16* dst = VT + ((long)b * HID + h0) * SEQL + s0;
#pragma unroll
  for (int rr = 0; rr < 4; ++rr) {
    const int hr = r + rr * 16;
    bf16x4 o = { tile[c + 0][hr], tile[c + 1][hr], tile[c + 2][hr], tile[c + 3][hr] };
    *reinterpret_cast<bf16x4*>(dst + (long)hr * SEQL + c) = o;
  }
}

extern "C" void kernel_launch(void* const* d_in, const int* in_sizes, int n_in,
                              void* d_out, int out_size, void* d_ws, size_t ws_size,
                              hipStream_t stream) {
  const float* x  = (const float*)d_in[0];
  const float* Wq = (const float*)d_in[1];
  const float* bq = (const float*)d_in[2];
  const float* Wk = (const float*)d_in[3];
  const float* bk = (const float*)d_in[4];
  const float* Wv = (const float*)d_in[5];
  const float* bv = (const float*)d_in[6];
  const float* Wo = (const float*)d_in[7];
  const float* bo = (const float*)d_in[8];
  float* out = (float*)d_out;

  // workspace (138.4 MiB peak), lifetime-safe aliasing as R2/R3:
  char* ws = (char*)d_ws;
  bf16*  XB    = (bf16*)(ws);
  bf16*  WQKVB = (bf16*)(ws + 16777216L);
  float* bqkv  = (float*)(ws + 23068672L);
  bf16*  AT    = (bf16*)(ws);
  bf16*  QKV   = (bf16*)(ws + 33554432L);
  bf16*  CTX   = (bf16*)(ws + 33554432L);
  bf16*  VT    = (bf16*)(ws + 83886080L);
  bf16*  WOB   = (bf16*)(ws + 100663296L);
  float* SCp   = (float*)(ws + 102760448L);

  const long MS = (long)NB * SEQL;  // 8192

  cast_f32_to_bf16<<<(int)(MS * HID / 4 / 256), 256, 0, stream>>>(x, XB, (int)(MS * HID / 4));
  cast_f32_to_bf16<<<1024, 256, 0, stream>>>(Wq, WQKVB, HID * HID / 4);
  cast_f32_to_bf16<<<1024, 256, 0, stream>>>(Wk, WQKVB + HID * HID, HID * HID / 4);
  cast_f32_to_bf16<<<1024, 256, 0, stream>>>(Wv, WQKVB + 2 * HID * HID, HID * HID / 4);
  cast_f32_to_bf16<<<1024, 256, 0, stream>>>(Wo, WOB, HID * HID / 4);
  concat_bias<<<12, 256, 0, stream>>>(bq, bk, bv, bqkv);

  // QKV projection: [8192,1024] x [3072,1024]^T; q-cols scaled 1/32
  gemm_nt<bf16, true, false, false, false, true><<<dim3(24, 32, 1), 512, 0, stream>>>(
      XB, WQKVB, bqkv, QKV, HID, HID, HID, 3 * HID, 0, 0, 0);

  transpose64<<<dim3(SEQL / 64, HID / 64, NB), 256, 0, stream>>>(QKV + 2 * HID, VT, 3 * HID);

  // scores = q.k^T -> packed lower-tri fp32 (128-tile granularity)
  gemm_nt<float, false, true, false, true, false><<<dim3(16, 8, NB), 512, 0, stream>>>(
      QKV, QKV + HID, nullptr, SCp, HID, 3 * HID, 3 * HID, SEQL,
      (long)SEQL * 3 * HID, (long)SEQL * 3 * HID, 0);

  softmax_causal<<<(int)(MS / 4), 256, 0, stream>>>(SCp, AT);

  // ctx = attn @ v (causal K-limit, 256-granular)
  gemm_nt<bf16, false, false, true, false, false><<<dim3(8, 8, NB), 512, 0, stream>>>(
      AT, VT, nullptr, CTX, SEQL, SEQL, SEQL, HID,
      (long)SEQL * SEQL, (long)HID * SEQL, (long)SEQL * HID);

  // out = ctx @ Wo^T + bo
  gemm_nt<float, true, false, false, false, false><<<dim3(8, 32, 1), 512, 0, stream>>>(
      CTX, WOB, bo, out, HID, HID, HID, HID, 0, 0, 0);
}